// Round 6
// baseline (99.705 us; speedup 1.0000x reference)
//
#include <hip/hip_runtime.h>
#include <hip/hip_bf16.h>
#include <stdint.h>

#define BN 8192
#define DK 256
#define KLOG2E_T 20.609929155556617f    // log2(e)/0.07
#define INV_T 14.285714285714286f       // 1/0.07
#define NEGINF (-3.0e38f)

typedef short vshort8 __attribute__((ext_vector_type(8)));
typedef float vfloat16 __attribute__((ext_vector_type(16)));

__device__ __forceinline__ void gload16(const void* g, void* lds) {
  __builtin_amdgcn_global_load_lds(
      (const __attribute__((address_space(1))) unsigned int*)g,
      (__attribute__((address_space(3))) unsigned int*)lds, 16, 0, 0);
}

// ---------- prep: fp32->bf16, keys, chains, cntA, G partials (one kernel) ----------
__global__ __launch_bounds__(256) void prep_g(
    const float* __restrict__ P, const int* __restrict__ aff,
    const int* __restrict__ inst, ushort* __restrict__ Pb,
    int* __restrict__ keys, int* __restrict__ head, int* __restrict__ nxt,
    int* __restrict__ cntA, float* __restrict__ G) {
  __shared__ float4 Gl[4][16][64];   // 16 KB; (rg,c) thread-private per a
  __shared__ int hist[16];
  const int t = threadIdx.x;
  const int rg = t >> 6, c = t & 63;
  for (int idx = t; idx < 4096; idx += 256)
    ((float4*)Gl)[idx] = make_float4(0.f, 0.f, 0.f, 0.f);
  if (t < 16) hist[t] = 0;
  __syncthreads();
  const int r0 = blockIdx.x * 64;
  for (int k = 0; k < 16; ++k) {
    const int r = r0 + k * 4 + rg;
    float4 v = ((const float4*)(P + (size_t)r * DK))[c];
    ushort4 h;
    __hip_bfloat16 b;
    b = __float2bfloat16(v.x); h.x = __builtin_bit_cast(unsigned short, b);
    b = __float2bfloat16(v.y); h.y = __builtin_bit_cast(unsigned short, b);
    b = __float2bfloat16(v.z); h.z = __builtin_bit_cast(unsigned short, b);
    b = __float2bfloat16(v.w); h.w = __builtin_bit_cast(unsigned short, b);
    ((ushort4*)(Pb + (size_t)r * DK))[c] = h;
    const int a = aff[r];
    float4 g = Gl[rg][a][c];
    g.x += v.x; g.y += v.y; g.z += v.z; g.w += v.w;
    Gl[rg][a][c] = g;
  }
  if (t < 64) {
    const int g = r0 + t;
    const int a = aff[g];
    const int k = (a << 12) | inst[g];
    keys[g] = k;
    nxt[g] = atomicExch(&head[k], g + 1);   // 0 = empty, rows stored +1
    atomicAdd(&hist[a], 1);
  }
  __syncthreads();
  if (t < 16) atomicAdd(&cntA[t], hist[t]);
  for (int idx = t; idx < 1024; idx += 256) {
    const int a = idx >> 6, cc = idx & 63;
    float4 s0 = Gl[0][a][cc], s1 = Gl[1][a][cc];
    float4 s2 = Gl[2][a][cc], s3 = Gl[3][a][cc];
    atomicAdd(&G[a * 256 + cc * 4 + 0], s0.x + s1.x + s2.x + s3.x);
    atomicAdd(&G[a * 256 + cc * 4 + 1], s0.y + s1.y + s2.y + s3.y);
    atomicAdd(&G[a * 256 + cc * 4 + 2], s0.z + s1.z + s2.z + s3.z);
    atomicAdd(&G[a * 256 + cc * 4 + 3], s0.w + s1.w + s2.w + s3.w);
  }
}

// ------------ fused GEMM (32x32x16, 256x256 block, 4 waves) + LSE partials ------------
// LDS rows are 128 B (64 bf16 = one kstep). 8 16B-slots per row, swizzle
// slot = gblk ^ (row&7) -> each 8-lane octet of a b128 read covers all 32
// banks exactly once (the layout that measured 0 conflicts in R1/R2).
__global__ __launch_bounds__(256, 1) void fused_kernel(
    const ushort* __restrict__ Pb, float2* __restrict__ stats) {
  __shared__ __align__(16) char Ab[2][32768];   // [buf][row 0..255][128B]
  __shared__ __align__(16) char Bb[2][32768];
  __shared__ float2 red[2][256];                // per-jw row partials

  const int tid = threadIdx.x;
  const int w = tid >> 6;        // 0..3
  const int l = tid & 63;
  const int lo = l & 31;
  const int hi = l >> 5;
  const int iw = w >> 1;         // 0..1 : 128 i-rows each
  const int jw = w & 1;          // 0..1 : 128 j-cols each

  const int bid = blockIdx.x;
  const int xcd = bid & 7;
  const int inner = (bid >> 3) & 3;
  const int it = bid >> 5;                    // 0..31
  const int jc = xcd * 4 + inner;             // 0..31 (XCD-locked j-chunk)
  const int ibase = it * 256;
  const int jcbase = jc * 256;

  // staging: thread t -> rows (t>>3)+32e, slot t&7; source block pre-swizzled
  const int trow = tid >> 3;                  // 0..31
  const int sswz = ((tid & 7) ^ (trow & 7)) * 16;
  const char* gA = (const char*)(Pb + (size_t)ibase * DK);
  const char* gB = (const char*)(Pb + (size_t)jcbase * DK);

#define STAGE(ks, bsel)                                                        \
  {                                                                            \
    const int ko = (ks) * 128;                                                 \
    _Pragma("unroll") for (int e = 0; e < 8; ++e) {                            \
      gload16(gA + (size_t)(trow + 32 * e) * 512 + ko + sswz,                  \
              Ab[bsel] + e * 4096 + tid * 16);                                 \
      gload16(gB + (size_t)(trow + 32 * e) * 512 + ko + sswz,                  \
              Bb[bsel] + e * 4096 + tid * 16);                                 \
    }                                                                          \
  }

  STAGE(0, 0);

  vfloat16 acc[4][4];
#pragma unroll
  for (int mi = 0; mi < 4; ++mi)
#pragma unroll
    for (int nj = 0; nj < 4; ++nj)
#pragma unroll
      for (int r = 0; r < 16; ++r) acc[mi][nj][r] = 0.f;

  const int rAb = iw * 128 + lo;   // + mi*32, row&7 == lo&7
  const int rBb = jw * 128 + lo;   // + nj*32

  __syncthreads();

  for (int ks = 0; ks < 4; ++ks) {
    if (ks < 3) STAGE(ks + 1, (ks + 1) & 1);
    const char* As = Ab[ks & 1];
    const char* Bs = Bb[ks & 1];
#pragma unroll
    for (int kk = 0; kk < 4; ++kk) {
      const int so = ((kk * 2 + hi) ^ (lo & 7)) * 16;
      vshort8 af0 = *(const vshort8*)(As + (rAb + 0) * 128 + so);
      vshort8 af1 = *(const vshort8*)(As + (rAb + 32) * 128 + so);
      vshort8 af2 = *(const vshort8*)(As + (rAb + 64) * 128 + so);
      vshort8 af3 = *(const vshort8*)(As + (rAb + 96) * 128 + so);
      vshort8 bf0 = *(const vshort8*)(Bs + (rBb + 0) * 128 + so);
      vshort8 bf1 = *(const vshort8*)(Bs + (rBb + 32) * 128 + so);
      vshort8 bf2 = *(const vshort8*)(Bs + (rBb + 64) * 128 + so);
      vshort8 bf3 = *(const vshort8*)(Bs + (rBb + 96) * 128 + so);
#pragma unroll
      for (int mi = 0; mi < 4; ++mi) {
        vshort8 af = mi == 0 ? af0 : mi == 1 ? af1 : mi == 2 ? af2 : af3;
        acc[mi][0] = __builtin_amdgcn_mfma_f32_32x32x16_bf16(bf0, af, acc[mi][0], 0, 0, 0);
        acc[mi][1] = __builtin_amdgcn_mfma_f32_32x32x16_bf16(bf1, af, acc[mi][1], 0, 0, 0);
        acc[mi][2] = __builtin_amdgcn_mfma_f32_32x32x16_bf16(bf2, af, acc[mi][2], 0, 0, 0);
        acc[mi][3] = __builtin_amdgcn_mfma_f32_32x32x16_bf16(bf3, af, acc[mi][3], 0, 0, 0);
      }
    }
    __syncthreads();
  }

  // ---- epilogue: self-mask, per-row (lane-local) max + exp-sum ----
  // D layout (swapped operands): lane lo = i-row (of frag), reg/hi = j-col.
#pragma unroll
  for (int mi = 0; mi < 4; ++mi) {
    const int gib = ibase + iw * 128 + mi * 32;
#pragma unroll
    for (int nj = 0; nj < 4; ++nj) {
      if (gib == (jcbase + jw * 128 + nj * 32)) {
#pragma unroll
        for (int r = 0; r < 16; ++r) {
          const int jj = (r & 3) + 8 * (r >> 2) + 4 * hi;
          if (jj == lo) acc[mi][nj][r] = NEGINF;
        }
      }
    }
  }
#pragma unroll
  for (int mi = 0; mi < 4; ++mi) {
    float mx = NEGINF;
#pragma unroll
    for (int nj = 0; nj < 4; ++nj)
#pragma unroll
      for (int r = 0; r < 16; ++r) mx = fmaxf(mx, acc[mi][nj][r]);
    mx = fmaxf(mx, __shfl_xor(mx, 32));
    const float rc = -mx * KLOG2E_T;
    float sv = 0.f;
#pragma unroll
    for (int nj = 0; nj < 4; ++nj)
#pragma unroll
      for (int r = 0; r < 16; ++r)
        sv += exp2f(fmaf(acc[mi][nj][r], KLOG2E_T, rc));
    sv += __shfl_xor(sv, 32);
    if (hi == 0) red[jw][iw * 128 + mi * 32 + lo] = make_float2(mx, sv);
  }
  __syncthreads();
  // merge the 2 j-waves per row, write stat slot jc
  {
    const float2 a = red[0][tid];
    const float2 b = red[1][tid];
    const float M = fmaxf(a.x, b.x);
    const float ss = a.y * exp2f((a.x - M) * KLOG2E_T) +
                     b.y * exp2f((b.x - M) * KLOG2E_T);
    stats[(size_t)jc * BN + ibase + tid] = make_float2(M, ss);
  }
#undef STAGE
}

// -------- per-row: merge 32 lse-partials + algebraic pos-sums --------
__global__ __launch_bounds__(256) void final_rows(
    const float2* __restrict__ stats, const float* __restrict__ P,
    const float* __restrict__ G, const int* __restrict__ keys,
    const int* __restrict__ head, const int* __restrict__ nxt,
    const int* __restrict__ cntA, float2* __restrict__ part) {
  const int t = threadIdx.x;
  const int rloc = t >> 6;    // 0..3
  const int lane = t & 63;
  const int i = blockIdx.x * 4 + rloc;

  // merge 32 (m,s) partials via shuffle tree (lanes replicated x2)
  float2 st = stats[(size_t)(lane & 31) * BN + i];
  float mm = st.x, ss = st.y;
#pragma unroll
  for (int off = 1; off < 32; off <<= 1) {
    float mo = __shfl_xor(mm, off);
    float so = __shfl_xor(ss, off);
    float M = fmaxf(mm, mo);
    ss = ss * exp2f((mm - M) * KLOG2E_T) + so * exp2f((mo - M) * KLOG2E_T);
    mm = M;
  }
  const float lse = logf(ss) + mm * INV_T;

  // Sum_pos sim = (P_i . G[a] - Sum_{key==} P_i . P_j) / T   (exact fp32)
  const int key = keys[i];
  const int a = key >> 12;
  float4 p4 = ((const float4*)(P + (size_t)i * 256))[lane];
  float4 g4 = ((const float4*)(G + a * 256))[lane];
  float acc = p4.x * g4.x + p4.y * g4.y + p4.z * g4.z + p4.w * g4.w;
  int cnt = 0;
  int j = head[key];
  while (j > 0) {                        // same-key rows (includes self), +1 enc
    const int jr = j - 1;
    float4 q4 = ((const float4*)(P + (size_t)jr * 256))[lane];
    acc -= p4.x * q4.x + p4.y * q4.y + p4.z * q4.z + p4.w * q4.w;
    cnt++;
    j = nxt[jr];
  }
#pragma unroll
  for (int off = 1; off < 64; off <<= 1) acc += __shfl_xor(acc, off);
  const float pc = (float)(cntA[a] - cnt);
  const float contrib = pc * lse - acc * INV_T;

  __shared__ float cs[4], ps[4];
  if (lane == 0) { cs[rloc] = contrib; ps[rloc] = pc; }
  __syncthreads();
  if (t == 0)
    part[blockIdx.x] = make_float2(cs[0] + cs[1] + cs[2] + cs[3],
                                   ps[0] + ps[1] + ps[2] + ps[3]);
}

__global__ void finalize(const float2* __restrict__ part, float* __restrict__ out) {
  const int t = threadIdx.x;   // 256 threads
  float c = 0.f, p = 0.f;
  for (int k = t; k < 2048; k += 256) {
    float2 v = part[k];
    c += v.x;
    p += v.y;
  }
#pragma unroll
  for (int off = 1; off < 64; off <<= 1) {
    c += __shfl_xor(c, off);
    p += __shfl_xor(p, off);
  }
  __shared__ float cs[4], ps[4];
  if ((t & 63) == 0) { cs[t >> 6] = c; ps[t >> 6] = p; }
  __syncthreads();
  if (t == 0) {
    c = cs[0] + cs[1] + cs[2] + cs[3];
    p = ps[0] + ps[1] + ps[2] + ps[3];
    out[0] = (p > 0.f) ? (c / p) : 0.f;
  }
}

extern "C" void kernel_launch(void* const* d_in, const int* in_sizes, int n_in,
                              void* d_out, int out_size, void* d_ws, size_t ws_size,
                              hipStream_t stream) {
  const float* P = (const float*)d_in[0];
  const int* aff = (const int*)d_in[1];
  const int* inst = (const int*)d_in[2];
  char* ws = (char*)d_ws;
  ushort* Pb    = (ushort*)(ws);                      // 4 MB
  int*    keys  = (int*)(ws + 4194304);               // 32 KB
  int*    nxt   = (int*)(ws + 4227072);               // 32 KB
  // --- zero region (one memset): head | G | cntA ---
  int*    head  = (int*)(ws + 4259840);               // 256 KB (65536 bins)
  float*  G     = (float*)(ws + 4521984);             // 16 KB (16x256)
  int*    cntA  = (int*)(ws + 4538368);               // 64 B
  float2* stats = (float2*)(ws + 4538496);            // 2 MB (32 x 8192 x 8B)
  float2* part  = (float2*)(ws + 6635648);            // 16 KB
  float* out = (float*)d_out;

  hipMemsetAsync(head, 0, 278592, stream);            // head..cntA = 0
  prep_g<<<128, 256, 0, stream>>>(P, aff, inst, Pb, keys, head, nxt, cntA, G);
  fused_kernel<<<1024, 256, 0, stream>>>(Pb, stats);
  final_rows<<<2048, 256, 0, stream>>>(stats, P, G, keys, head, nxt, cntA, part);
  finalize<<<1, 256, 0, stream>>>(part, out);
}

// Round 7
// 89.672 us; speedup vs baseline: 1.1119x; 1.1119x over previous
//
#include <hip/hip_runtime.h>
#include <hip/hip_bf16.h>
#include <stdint.h>

#define BN 8192
#define DK 256
#define KLOG2E_T 20.609929155556617f    // log2(e)/0.07
#define INV_T 14.285714285714286f       // 1/0.07
#define NEGINF (-3.0e38f)

typedef short vshort8 __attribute__((ext_vector_type(8)));
typedef float vfloat16 __attribute__((ext_vector_type(16)));

__device__ __forceinline__ void gload16(const void* g, void* lds) {
  __builtin_amdgcn_global_load_lds(
      (const __attribute__((address_space(1))) unsigned int*)g,
      (__attribute__((address_space(3))) unsigned int*)lds, 16, 0, 0);
}

// ---------- prep: fp32->bf16, keys, chains, cntA, G partials (one kernel) ----------
__global__ __launch_bounds__(256) void prep_g(
    const float* __restrict__ P, const int* __restrict__ aff,
    const int* __restrict__ inst, ushort* __restrict__ Pb,
    int* __restrict__ keys, int* __restrict__ head, int* __restrict__ nxt,
    int* __restrict__ cntA, float* __restrict__ G) {
  __shared__ float4 Gl[4][16][64];   // 16 KB; (rg,c) thread-private per a
  __shared__ int hist[16];
  const int t = threadIdx.x;
  const int rg = t >> 6, c = t & 63;
  for (int idx = t; idx < 4096; idx += 256)
    ((float4*)Gl)[idx] = make_float4(0.f, 0.f, 0.f, 0.f);
  if (t < 16) hist[t] = 0;
  __syncthreads();
  const int r0 = blockIdx.x * 64;
  for (int k = 0; k < 16; ++k) {
    const int r = r0 + k * 4 + rg;
    float4 v = ((const float4*)(P + (size_t)r * DK))[c];
    ushort4 h;
    __hip_bfloat16 b;
    b = __float2bfloat16(v.x); h.x = __builtin_bit_cast(unsigned short, b);
    b = __float2bfloat16(v.y); h.y = __builtin_bit_cast(unsigned short, b);
    b = __float2bfloat16(v.z); h.z = __builtin_bit_cast(unsigned short, b);
    b = __float2bfloat16(v.w); h.w = __builtin_bit_cast(unsigned short, b);
    ((ushort4*)(Pb + (size_t)r * DK))[c] = h;
    const int a = aff[r];
    float4 g = Gl[rg][a][c];
    g.x += v.x; g.y += v.y; g.z += v.z; g.w += v.w;
    Gl[rg][a][c] = g;
  }
  if (t < 64) {
    const int g = r0 + t;
    const int a = aff[g];
    const int k = (a << 12) | inst[g];
    keys[g] = k;
    nxt[g] = atomicExch(&head[k], g + 1);   // 0 = empty, rows stored +1
    atomicAdd(&hist[a], 1);
  }
  __syncthreads();
  if (t < 16) atomicAdd(&cntA[t], hist[t]);
  for (int idx = t; idx < 1024; idx += 256) {
    const int a = idx >> 6, cc = idx & 63;
    float4 s0 = Gl[0][a][cc], s1 = Gl[1][a][cc];
    float4 s2 = Gl[2][a][cc], s3 = Gl[3][a][cc];
    atomicAdd(&G[a * 256 + cc * 4 + 0], s0.x + s1.x + s2.x + s3.x);
    atomicAdd(&G[a * 256 + cc * 4 + 1], s0.y + s1.y + s2.y + s3.y);
    atomicAdd(&G[a * 256 + cc * 4 + 2], s0.z + s1.z + s2.z + s3.z);
    atomicAdd(&G[a * 256 + cc * 4 + 3], s0.w + s1.w + s2.w + s3.w);
  }
}

// ---- fused GEMM (32x32x16, 256x256 tile, 8 waves, phase-scheduled) + LSE ----
// LDS row = one K-tile row = 64 bf16 = 128 B = 8 16B-slots.
// Swizzle: slot = gblk ^ (row&7) ^ 5*((row>>3)&1). Rows r,r+8 differ, only
// (r,r+16) share a slot (2-way = free). Source pre-swizzled, LDS dest linear.
__global__ __launch_bounds__(512, 1) void fused_kernel(
    const ushort* __restrict__ Pb, float2* __restrict__ stats) {
  __shared__ __align__(16) char Ab[2][32768];   // [buf][row 0..255][128B]
  __shared__ __align__(16) char Bb[2][32768];
  __shared__ float2 red[4][256];                // 8KB epilogue merge

  const int tid = threadIdx.x;
  const int w = tid >> 6;        // 0..7
  const int l = tid & 63;
  const int lo = l & 31;
  const int hi = l >> 5;
  const int iw = w >> 2;         // 0..1 : 128 i-rows each
  const int jw = w & 3;          // 0..3 : 64 j-cols each

  const int bid = blockIdx.x;
  const int xcd = bid & 7;
  const int inner = (bid >> 3) & 3;
  const int it = bid >> 5;                    // 0..31
  const int jc = xcd * 4 + inner;             // 0..31 (XCD-locked j-chunk)
  const int ibase = it * 256;
  const int jcbase = jc * 256;

  // staging: thread t -> rows (t>>3) + 64e, slot t&7; source pre-swizzled
  const int srow = tid >> 3;                  // 0..63
  const int sswz = ((tid & 7) ^ (srow & 7) ^ (5 * ((srow >> 3) & 1))) * 16;
  const char* gA = (const char*)(Pb + (size_t)ibase * DK);
  const char* gB = (const char*)(Pb + (size_t)jcbase * DK);

#define STAGE(kt1, bsel)                                                       \
  {                                                                            \
    const int ko = (kt1) * 128;                                                \
    _Pragma("unroll") for (int e = 0; e < 4; ++e) {                            \
      gload16(gA + (size_t)(srow + 64 * e) * 512 + ko + sswz,                  \
              Ab[bsel] + e * 8192 + tid * 16);                                 \
      gload16(gB + (size_t)(srow + 64 * e) * 512 + ko + sswz,                  \
              Bb[bsel] + e * 8192 + tid * 16);                                 \
    }                                                                          \
  }
#define BARRIER asm volatile("s_barrier" ::: "memory")
#define DRAIN_BARRIER asm volatile("s_waitcnt vmcnt(0)\ns_barrier" ::: "memory")

  // per-lane read constants
  const int rswz = (lo & 7) ^ (5 * ((lo >> 3) & 1));
  int swzk[4];
#pragma unroll
  for (int kk = 0; kk < 4; ++kk) swzk[kk] = ((kk * 2 + hi) ^ rswz) * 16;
  const int rowAb0 = (iw * 128 + lo) * 128;        // + mi*32*128
  const int rowBb0 = (jw * 64 + lo) * 128;         // + nj*32*128

  vfloat16 acc[4][2];
#pragma unroll
  for (int mi = 0; mi < 4; ++mi)
#pragma unroll
    for (int nj = 0; nj < 2; ++nj)
#pragma unroll
      for (int r = 0; r < 16; ++r) acc[mi][nj][r] = 0.f;

  // prologue: stage K-tile 0, drain, enter
  STAGE(0, 0);
  DRAIN_BARRIER;

  for (int kt = 0; kt < 4; ++kt) {
    const int s = kt & 1;
    if (kt < 3) STAGE(kt + 1, s ^ 1);      // issue early, drain at boundary
    const char* As = Ab[s];
    const char* Bs = Bb[s];

    // ---- phase 0: read B (both nj, all kk) + A (mi 0,1); MFMA mp0 ----
    vshort8 bf[2][4], af[2][4];
#pragma unroll
    for (int nj = 0; nj < 2; ++nj)
#pragma unroll
      for (int kk = 0; kk < 4; ++kk)
        bf[nj][kk] = *(const vshort8*)(Bs + rowBb0 + nj * 4096 + swzk[kk]);
#pragma unroll
    for (int mi = 0; mi < 2; ++mi)
#pragma unroll
      for (int kk = 0; kk < 4; ++kk)
        af[mi][kk] = *(const vshort8*)(As + rowAb0 + mi * 4096 + swzk[kk]);
    __builtin_amdgcn_s_setprio(1);
#pragma unroll
    for (int kk = 0; kk < 4; ++kk)
#pragma unroll
      for (int mi = 0; mi < 2; ++mi) {
        acc[mi][0] = __builtin_amdgcn_mfma_f32_32x32x16_bf16(bf[0][kk], af[mi][kk], acc[mi][0], 0, 0, 0);
        acc[mi][1] = __builtin_amdgcn_mfma_f32_32x32x16_bf16(bf[1][kk], af[mi][kk], acc[mi][1], 0, 0, 0);
      }
    __builtin_amdgcn_s_setprio(0);
    BARRIER;

    // ---- phase 1: read A (mi 2,3); MFMA mp1 ----
#pragma unroll
    for (int mi = 0; mi < 2; ++mi)
#pragma unroll
      for (int kk = 0; kk < 4; ++kk)
        af[mi][kk] = *(const vshort8*)(As + rowAb0 + (mi + 2) * 4096 + swzk[kk]);
    __builtin_amdgcn_s_setprio(1);
#pragma unroll
    for (int kk = 0; kk < 4; ++kk)
#pragma unroll
      for (int mi = 0; mi < 2; ++mi) {
        acc[mi + 2][0] = __builtin_amdgcn_mfma_f32_32x32x16_bf16(bf[0][kk], af[mi][kk], acc[mi + 2][0], 0, 0, 0);
        acc[mi + 2][1] = __builtin_amdgcn_mfma_f32_32x32x16_bf16(bf[1][kk], af[mi][kk], acc[mi + 2][1], 0, 0, 0);
      }
    __builtin_amdgcn_s_setprio(0);
    DRAIN_BARRIER;                          // next tile's loads land here
  }

  // ---- epilogue: self-mask, per-i-row max + exp-sum (D[j][i]: col=lane=i) ----
#pragma unroll
  for (int mi = 0; mi < 4; ++mi) {
    const int gib = ibase + iw * 128 + mi * 32;
#pragma unroll
    for (int nj = 0; nj < 2; ++nj) {
      if (gib == (jcbase + jw * 64 + nj * 32)) {
#pragma unroll
        for (int r = 0; r < 16; ++r) {
          const int jj = (r & 3) + 8 * (r >> 2) + 4 * hi;
          if (jj == lo) acc[mi][nj][r] = NEGINF;
        }
      }
    }
  }
#pragma unroll
  for (int mi = 0; mi < 4; ++mi) {
    float mx = NEGINF;
#pragma unroll
    for (int nj = 0; nj < 2; ++nj)
#pragma unroll
      for (int r = 0; r < 16; ++r) mx = fmaxf(mx, acc[mi][nj][r]);
    mx = fmaxf(mx, __shfl_xor(mx, 32));
    const float rc = -mx * KLOG2E_T;
    float sv = 0.f;
#pragma unroll
    for (int nj = 0; nj < 2; ++nj)
#pragma unroll
      for (int r = 0; r < 16; ++r)
        sv += exp2f(fmaf(acc[mi][nj][r], KLOG2E_T, rc));
    sv += __shfl_xor(sv, 32);
    if (hi == 0) red[jw][iw * 128 + mi * 32 + lo] = make_float2(mx, sv);
  }
  __syncthreads();
  if (tid < 256) {  // merge the 4 j-waves per row, write stat slot jc
    float2 a = red[0][tid];
    float mm = a.x, ss = a.y;
#pragma unroll
    for (int j2 = 1; j2 < 4; ++j2) {
      float2 b = red[j2][tid];
      float M = fmaxf(mm, b.x);
      ss = ss * exp2f((mm - M) * KLOG2E_T) + b.y * exp2f((b.x - M) * KLOG2E_T);
      mm = M;
    }
    stats[(size_t)jc * BN + ibase + tid] = make_float2(mm, ss);
  }
#undef STAGE
#undef BARRIER
#undef DRAIN_BARRIER
}

// -------- per-row: merge 32 lse-partials + algebraic pos-sums --------
__global__ __launch_bounds__(256) void final_rows(
    const float2* __restrict__ stats, const float* __restrict__ P,
    const float* __restrict__ G, const int* __restrict__ keys,
    const int* __restrict__ head, const int* __restrict__ nxt,
    const int* __restrict__ cntA, float2* __restrict__ part) {
  const int t = threadIdx.x;
  const int rloc = t >> 6;    // 0..3
  const int lane = t & 63;
  const int i = blockIdx.x * 4 + rloc;

  // merge 32 (m,s) partials via shuffle tree (lanes replicated x2)
  float2 st = stats[(size_t)(lane & 31) * BN + i];
  float mm = st.x, ss = st.y;
#pragma unroll
  for (int off = 1; off < 32; off <<= 1) {
    float mo = __shfl_xor(mm, off);
    float so = __shfl_xor(ss, off);
    float M = fmaxf(mm, mo);
    ss = ss * exp2f((mm - M) * KLOG2E_T) + so * exp2f((mo - M) * KLOG2E_T);
    mm = M;
  }
  const float lse = logf(ss) + mm * INV_T;

  // Sum_pos sim = (P_i . G[a] - Sum_{key==} P_i . P_j) / T   (exact fp32)
  const int key = keys[i];
  const int a = key >> 12;
  float4 p4 = ((const float4*)(P + (size_t)i * 256))[lane];
  float4 g4 = ((const float4*)(G + a * 256))[lane];
  float acc = p4.x * g4.x + p4.y * g4.y + p4.z * g4.z + p4.w * g4.w;
  int cnt = 0;
  int j = head[key];
  while (j > 0) {                        // same-key rows (includes self), +1 enc
    const int jr = j - 1;
    float4 q4 = ((const float4*)(P + (size_t)jr * 256))[lane];
    acc -= p4.x * q4.x + p4.y * q4.y + p4.z * q4.z + p4.w * q4.w;
    cnt++;
    j = nxt[jr];
  }
#pragma unroll
  for (int off = 1; off < 64; off <<= 1) acc += __shfl_xor(acc, off);
  const float pc = (float)(cntA[a] - cnt);
  const float contrib = pc * lse - acc * INV_T;

  __shared__ float cs[4], ps[4];
  if (lane == 0) { cs[rloc] = contrib; ps[rloc] = pc; }
  __syncthreads();
  if (t == 0)
    part[blockIdx.x] = make_float2(cs[0] + cs[1] + cs[2] + cs[3],
                                   ps[0] + ps[1] + ps[2] + ps[3]);
}

__global__ void finalize(const float2* __restrict__ part, float* __restrict__ out) {
  const int t = threadIdx.x;   // 256 threads
  float c = 0.f, p = 0.f;
  for (int k = t; k < 2048; k += 256) {
    float2 v = part[k];
    c += v.x;
    p += v.y;
  }
#pragma unroll
  for (int off = 1; off < 64; off <<= 1) {
    c += __shfl_xor(c, off);
    p += __shfl_xor(p, off);
  }
  __shared__ float cs[4], ps[4];
  if ((t & 63) == 0) { cs[t >> 6] = c; ps[t >> 6] = p; }
  __syncthreads();
  if (t == 0) {
    c = cs[0] + cs[1] + cs[2] + cs[3];
    p = ps[0] + ps[1] + ps[2] + ps[3];
    out[0] = (p > 0.f) ? (c / p) : 0.f;
  }
}

extern "C" void kernel_launch(void* const* d_in, const int* in_sizes, int n_in,
                              void* d_out, int out_size, void* d_ws, size_t ws_size,
                              hipStream_t stream) {
  const float* P = (const float*)d_in[0];
  const int* aff = (const int*)d_in[1];
  const int* inst = (const int*)d_in[2];
  char* ws = (char*)d_ws;
  ushort* Pb    = (ushort*)(ws);                      // 4 MB
  int*    keys  = (int*)(ws + 4194304);               // 32 KB
  int*    nxt   = (int*)(ws + 4227072);               // 32 KB
  // --- zero region (one memset): head | G | cntA ---
  int*    head  = (int*)(ws + 4259840);               // 256 KB (65536 bins)
  float*  G     = (float*)(ws + 4521984);             // 16 KB (16x256)
  int*    cntA  = (int*)(ws + 4538368);               // 64 B
  float2* stats = (float2*)(ws + 4538496);            // 2 MB (32 x 8192 x 8B)
  float2* part  = (float2*)(ws + 6635648);            // 16 KB
  float* out = (float*)d_out;

  hipMemsetAsync(head, 0, 278592, stream);            // head..cntA = 0
  prep_g<<<128, 256, 0, stream>>>(P, aff, inst, Pb, keys, head, nxt, cntA, G);
  fused_kernel<<<1024, 512, 0, stream>>>(Pb, stats);
  final_rows<<<2048, 256, 0, stream>>>(stats, P, G, keys, head, nxt, cntA, part);
  finalize<<<1, 256, 0, stream>>>(part, out);
}